// Round 1
// baseline (1319.353 us; speedup 1.0000x reference)
//
#include <hip/hip_runtime.h>
#include <math.h>

#define D 64

// ---- CSR build ----------------------------------------------------------

__global__ void count_edges(const int* __restrict__ dst, int* __restrict__ counts, int E) {
    int e = blockIdx.x * blockDim.x + threadIdx.x;
    if (e < E) atomicAdd(&counts[dst[e]], 1);
}

// Single-workgroup exclusive scan of counts -> offsets; also emits norm = rsqrt(max(deg,1)).
__global__ void scan_counts(const int* __restrict__ counts, int* __restrict__ offsets,
                            float* __restrict__ norm, int n) {
    __shared__ int tmp[1024];
    int carry = 0;
    for (int base = 0; base < n; base += 1024) {
        int i = base + (int)threadIdx.x;
        int v = (i < n) ? counts[i] : 0;
        tmp[threadIdx.x] = v;
        __syncthreads();
        for (int off = 1; off < 1024; off <<= 1) {
            int t = (threadIdx.x >= (unsigned)off) ? tmp[threadIdx.x - off] : 0;
            __syncthreads();
            tmp[threadIdx.x] += t;
            __syncthreads();
        }
        if (i < n) {
            offsets[i] = carry + tmp[threadIdx.x] - v;              // exclusive
            norm[i] = rsqrtf((float)(v > 1 ? v : 1));
        }
        int total = tmp[1023];
        __syncthreads();          // protect tmp before next chunk overwrites
        carry += total;
    }
    if (threadIdx.x == 0) offsets[n] = carry;
}

__global__ void fill_csr(const int* __restrict__ src, const int* __restrict__ dst,
                         const int* __restrict__ offsets, int* __restrict__ cursor,
                         int* __restrict__ csr, int E) {
    int e = blockIdx.x * blockDim.x + threadIdx.x;
    if (e < E) {
        int v = dst[e];
        int pos = atomicAdd(&cursor[v], 1);
        csr[offsets[v] + pos] = src[e];
    }
}

// ---- hop 0: out = sigmoid(f.s)*f ; g0 = f*norm --------------------------

__global__ void hop0(const float* __restrict__ feat, const float* __restrict__ s,
                     const float* __restrict__ norm, float* __restrict__ g,
                     float* __restrict__ out, int n) {
    int lane = threadIdx.x & 63;
    int node = blockIdx.x * 4 + (threadIdx.x >> 6);
    if (node >= n) return;
    float f  = feat[node * D + lane];
    float dot = f * s[lane];
    #pragma unroll
    for (int m = 32; m >= 1; m >>= 1) dot += __shfl_xor(dot, m, 64);
    float sig = 1.0f / (1.0f + expf(-dot));
    out[node * D + lane] = sig * f;
    g[node * D + lane]   = f * norm[node];
}

// ---- hop t: gather-SpMM + fused attention-pool epilogue -----------------
// gin = norm .* h_{t-1}. agg[v] = sum_{e: dst=v} gin[src]. h = agg*norm.
// gout = h*norm (input to next hop). out += sigmoid(h.s)*h.

__global__ void spmm_hop(const float* __restrict__ gin, const int* __restrict__ offsets,
                         const int* __restrict__ csr, const float* __restrict__ norm,
                         const float* __restrict__ s, float* __restrict__ gout,
                         float* __restrict__ out, int n) {
    int lane = threadIdx.x & 63;
    int node = blockIdx.x * 4 + (threadIdx.x >> 6);
    if (node >= n) return;
    int beg = offsets[node], end = offsets[node + 1];
    float sum = 0.f;
    int i = beg;
    // unroll x4: 4 independent gathers in flight per wave
    for (; i + 4 <= end; i += 4) {
        int u0 = csr[i], u1 = csr[i + 1], u2 = csr[i + 2], u3 = csr[i + 3];
        float a = gin[u0 * D + lane];
        float b = gin[u1 * D + lane];
        float c = gin[u2 * D + lane];
        float d = gin[u3 * D + lane];
        sum += (a + b) + (c + d);
    }
    for (; i < end; ++i) sum += gin[csr[i] * D + lane];
    float nv = norm[node];
    float h  = sum * nv;
    gout[node * D + lane] = h * nv;
    float dot = h * s[lane];
    #pragma unroll
    for (int m = 32; m >= 1; m >>= 1) dot += __shfl_xor(dot, m, 64);
    float sig = 1.0f / (1.0f + expf(-dot));
    out[node * D + lane] += sig * h;
}

// ---- launcher -----------------------------------------------------------

extern "C" void kernel_launch(void* const* d_in, const int* in_sizes, int n_in,
                              void* d_out, int out_size, void* d_ws, size_t ws_size,
                              hipStream_t stream) {
    const float* feat = (const float*)d_in[0];
    const float* s    = (const float*)d_in[1];
    const int*   src  = (const int*)d_in[2];
    const int*   dst  = (const int*)d_in[3];
    // d_in[4] = k (always 10 in this problem); loop count must be static anyway.
    const int K = 10;

    int N = in_sizes[0] / D;
    int E = in_sizes[2];

    // workspace layout (all 4B types)
    int*   counts  = (int*)d_ws;               // N
    int*   cursor  = counts + N;               // N
    int*   offsets = cursor + N;               // N+1
    int*   csr     = offsets + (N + 1);        // E
    float* norm    = (float*)(csr + E);        // N
    float* g0      = norm + N;                 // N*D
    float* g1      = g0 + (size_t)N * D;       // N*D

    hipMemsetAsync(counts, 0, sizeof(int) * 2 * (size_t)N, stream);  // counts + cursor

    count_edges<<<(E + 255) / 256, 256, 0, stream>>>(dst, counts, E);
    scan_counts<<<1, 1024, 0, stream>>>(counts, offsets, norm, N);
    fill_csr<<<(E + 255) / 256, 256, 0, stream>>>(src, dst, offsets, cursor, csr, E);

    int nb = (N + 3) / 4;   // 4 waves (nodes) per 256-thread block
    hop0<<<nb, 256, 0, stream>>>(feat, s, norm, g0, (float*)d_out, N);

    float* gin = g0; float* gout = g1;
    for (int t = 0; t < K; ++t) {
        spmm_hop<<<nb, 256, 0, stream>>>(gin, offsets, csr, norm, s, gout, (float*)d_out, N);
        float* tmp = gin; gin = gout; gout = tmp;
    }
}

// Round 2
// 1093.353 us; speedup vs baseline: 1.2067x; 1.2067x over previous
//
#include <hip/hip_runtime.h>
#include <math.h>

#define D 64
#define D4 16  // D/4 float4s per row

__device__ __forceinline__ float4 f4add(float4 a, float4 b) {
    return make_float4(a.x + b.x, a.y + b.y, a.z + b.z, a.w + b.w);
}
__device__ __forceinline__ float4 f4scale(float4 a, float b) {
    return make_float4(a.x * b, a.y * b, a.z * b, a.w * b);
}

// ---- CSR build ----------------------------------------------------------

__global__ void count_edges(const int* __restrict__ dst, int* __restrict__ counts, int E) {
    int e = blockIdx.x * blockDim.x + threadIdx.x;
    if (e < E) atomicAdd(&counts[dst[e]], 1);
}

// phase 1: per-1024-chunk sums. 256 threads/block, 4 elements/thread.
__global__ void block_sums(const int* __restrict__ counts, int* __restrict__ bsum, int n) {
    int base = blockIdx.x * 1024;
    int t = threadIdx.x;
    int v = 0;
    #pragma unroll
    for (int j = 0; j < 4; ++j) {
        int i = base + t + j * 256;
        if (i < n) v += counts[i];
    }
    #pragma unroll
    for (int m = 32; m >= 1; m >>= 1) v += __shfl_xor(v, m, 64);
    __shared__ int ws[4];
    if ((t & 63) == 0) ws[t >> 6] = v;
    __syncthreads();
    if (t == 0) bsum[blockIdx.x] = ws[0] + ws[1] + ws[2] + ws[3];
}

// phase 2: one-block exclusive scan of the chunk sums (nb <= 1024); writes total.
__global__ void scan_bsums(int* __restrict__ bsum, int nb, int* __restrict__ offsets, int n) {
    __shared__ int tmp[1024];
    int t = threadIdx.x;
    int v = (t < nb) ? bsum[t] : 0;
    tmp[t] = v;
    __syncthreads();
    for (int off = 1; off < 1024; off <<= 1) {
        int x = (t >= off) ? tmp[t - off] : 0;
        __syncthreads();
        tmp[t] += x;
        __syncthreads();
    }
    if (t < nb) bsum[t] = tmp[t] - v;      // exclusive base per chunk
    if (t == 1023) offsets[n] = tmp[1023]; // grand total
}

// phase 3: per-chunk local scan + chunk base; also emit norm.
__global__ void scan_block(const int* __restrict__ counts, const int* __restrict__ bsum,
                           int* __restrict__ offsets, float* __restrict__ norm, int n) {
    __shared__ int tmp[1024];
    int base = blockIdx.x * 1024;
    int t = threadIdx.x;
    int i = base + t;
    int v = (i < n) ? counts[i] : 0;
    tmp[t] = v;
    __syncthreads();
    for (int off = 1; off < 1024; off <<= 1) {
        int x = (t >= off) ? tmp[t - off] : 0;
        __syncthreads();
        tmp[t] += x;
        __syncthreads();
    }
    if (i < n) {
        offsets[i] = bsum[blockIdx.x] + tmp[t] - v;
        norm[i] = rsqrtf((float)(v > 1 ? v : 1));
    }
}

__global__ void fill_csr(const int* __restrict__ src, const int* __restrict__ dst,
                         const int* __restrict__ offsets, int* __restrict__ cursor,
                         int* __restrict__ csr, int E) {
    int e = blockIdx.x * blockDim.x + threadIdx.x;
    if (e < E) {
        int v = dst[e];
        int pos = atomicAdd(&cursor[v], 1);
        csr[offsets[v] + pos] = src[e];
    }
}

// ---- hop 0: out = sigmoid(f.s)*f ; g0 = f*norm --------------------------
// 16 lanes per node, float4 per lane.

__global__ void hop0(const float4* __restrict__ feat, const float4* __restrict__ s4,
                     const float* __restrict__ norm, float4* __restrict__ g,
                     float4* __restrict__ out, int n) {
    int t = blockIdx.x * blockDim.x + threadIdx.x;
    int node = t >> 4;
    int l = t & 15;
    if (node >= n) return;
    float4 f = feat[node * D4 + l];
    float4 sv = s4[l];
    float dot = f.x * sv.x + f.y * sv.y + f.z * sv.z + f.w * sv.w;
    #pragma unroll
    for (int m = 1; m <= 8; m <<= 1) dot += __shfl_xor(dot, m, 64);
    float sig = 1.0f / (1.0f + expf(-dot));
    out[node * D4 + l] = f4scale(f, sig);
    g[node * D4 + l]   = f4scale(f, norm[node]);
}

// ---- hop t: gather-SpMM + fused attention-pool epilogue -----------------
// wave per node; lane = 16*g + l. Subgroup g gathers edges beg+g, beg+g+4,...
// as 16-lane float4 rows (dwordx4, 1 KiB per wave instruction, 4 edges/instr).

__global__ void spmm_hop(const float4* __restrict__ gin, const int* __restrict__ offsets,
                         const int* __restrict__ csr, const float* __restrict__ norm,
                         const float4* __restrict__ s4, float4* __restrict__ gout,
                         float4* __restrict__ out, int n) {
    int lane = threadIdx.x & 63;
    int node = blockIdx.x * 4 + (threadIdx.x >> 6);
    if (node >= n) return;
    int g = lane >> 4;
    int l = lane & 15;
    int beg = offsets[node], end = offsets[node + 1];
    float4 sum = make_float4(0.f, 0.f, 0.f, 0.f);
    int i = beg + g;
    // x2 unroll: 8 edges in flight per wave
    for (; i + 4 < end; i += 8) {
        int u0 = csr[i], u1 = csr[i + 4];
        float4 a = gin[u0 * D4 + l];
        float4 b = gin[u1 * D4 + l];
        sum = f4add(sum, f4add(a, b));
    }
    for (; i < end; i += 4) sum = f4add(sum, gin[csr[i] * D4 + l]);
    // reduce across the 4 edge-subgroups (lane bits 4,5)
    #pragma unroll
    for (int m = 16; m <= 32; m <<= 1) {
        sum.x += __shfl_xor(sum.x, m, 64);
        sum.y += __shfl_xor(sum.y, m, 64);
        sum.z += __shfl_xor(sum.z, m, 64);
        sum.w += __shfl_xor(sum.w, m, 64);
    }
    float nv = norm[node];
    float4 h = f4scale(sum, nv);
    float4 sv = s4[l];
    float dot = h.x * sv.x + h.y * sv.y + h.z * sv.z + h.w * sv.w;
    #pragma unroll
    for (int m = 1; m <= 8; m <<= 1) dot += __shfl_xor(dot, m, 64);
    float sig = 1.0f / (1.0f + expf(-dot));
    if (g == 0) {
        gout[node * D4 + l] = f4scale(h, nv);
        float4 o = out[node * D4 + l];
        o.x += sig * h.x; o.y += sig * h.y; o.z += sig * h.z; o.w += sig * h.w;
        out[node * D4 + l] = o;
    }
}

// ---- launcher -----------------------------------------------------------

extern "C" void kernel_launch(void* const* d_in, const int* in_sizes, int n_in,
                              void* d_out, int out_size, void* d_ws, size_t ws_size,
                              hipStream_t stream) {
    const float* feat = (const float*)d_in[0];
    const float* s    = (const float*)d_in[1];
    const int*   src  = (const int*)d_in[2];
    const int*   dst  = (const int*)d_in[3];
    const int K = 10;

    int N = in_sizes[0] / D;
    int E = in_sizes[2];
    int nchunks = (N + 1023) / 1024;   // 98 for N=100000 (must be <= 1024)

    // workspace layout (all 4B types)
    int*   counts  = (int*)d_ws;               // N
    int*   cursor  = counts + N;               // N
    int*   offsets = cursor + N;               // N+1
    int*   csr     = offsets + (N + 1);        // E
    float* norm    = (float*)(csr + E);        // N
    float* g0      = norm + N;                 // N*D
    float* g1      = g0 + (size_t)N * D;       // N*D
    int*   bsum    = (int*)(g1 + (size_t)N * D); // nchunks

    hipMemsetAsync(counts, 0, sizeof(int) * 2 * (size_t)N, stream);  // counts + cursor

    count_edges<<<(E + 255) / 256, 256, 0, stream>>>(dst, counts, E);
    block_sums<<<nchunks, 256, 0, stream>>>(counts, bsum, N);
    scan_bsums<<<1, 1024, 0, stream>>>(bsum, nchunks, offsets, N);
    scan_block<<<nchunks, 1024, 0, stream>>>(counts, bsum, offsets, norm, N);
    fill_csr<<<(E + 255) / 256, 256, 0, stream>>>(src, dst, offsets, cursor, csr, E);

    hop0<<<(N * 16 + 255) / 256, 256, 0, stream>>>(
        (const float4*)feat, (const float4*)s, norm, (float4*)g0, (float4*)d_out, N);

    float* gin = g0; float* gout = g1;
    for (int t = 0; t < K; ++t) {
        spmm_hop<<<(N + 3) / 4, 256, 0, stream>>>(
            (const float4*)gin, offsets, csr, norm, (const float4*)s,
            (float4*)gout, (float4*)d_out, N);
        float* tmp = gin; gin = gout; gout = tmp;
    }
}

// Round 4
// 682.351 us; speedup vs baseline: 1.9335x; 1.6023x over previous
//
#include <hip/hip_runtime.h>
#include <math.h>

#define D 64

// ---- helpers ------------------------------------------------------------

__device__ __forceinline__ float4 f4scale(float4 a, float b) {
    return make_float4(a.x * b, a.y * b, a.z * b, a.w * b);
}

__device__ __forceinline__ unsigned int bf16_rne(float x) {
    unsigned int u = __float_as_uint(x);
    u += 0x7fffu + ((u >> 16) & 1u);
    return u >> 16;
}

__device__ __forceinline__ uint4 pack_bf16x8(const float* v) {
    uint4 p;
    p.x = bf16_rne(v[0]) | (bf16_rne(v[1]) << 16);
    p.y = bf16_rne(v[2]) | (bf16_rne(v[3]) << 16);
    p.z = bf16_rne(v[4]) | (bf16_rne(v[5]) << 16);
    p.w = bf16_rne(v[6]) | (bf16_rne(v[7]) << 16);
    return p;
}

__device__ __forceinline__ void acc_bf16x8(uint4 p, float* a) {
    a[0] += __uint_as_float(p.x << 16);
    a[1] += __uint_as_float(p.x & 0xffff0000u);
    a[2] += __uint_as_float(p.y << 16);
    a[3] += __uint_as_float(p.y & 0xffff0000u);
    a[4] += __uint_as_float(p.z << 16);
    a[5] += __uint_as_float(p.z & 0xffff0000u);
    a[6] += __uint_as_float(p.w << 16);
    a[7] += __uint_as_float(p.w & 0xffff0000u);
}

// ---- CSR build ----------------------------------------------------------

__global__ void count_edges(const int* __restrict__ dst, int* __restrict__ counts, int E) {
    int e = blockIdx.x * blockDim.x + threadIdx.x;
    if (e < E) atomicAdd(&counts[dst[e]], 1);
}

__global__ void block_sums(const int* __restrict__ counts, int* __restrict__ bsum, int n) {
    int base = blockIdx.x * 1024;
    int t = threadIdx.x;
    int v = 0;
    #pragma unroll
    for (int j = 0; j < 4; ++j) {
        int i = base + t + j * 256;
        if (i < n) v += counts[i];
    }
    #pragma unroll
    for (int m = 32; m >= 1; m >>= 1) v += __shfl_xor(v, m, 64);
    __shared__ int ws[4];
    if ((t & 63) == 0) ws[t >> 6] = v;
    __syncthreads();
    if (t == 0) bsum[blockIdx.x] = ws[0] + ws[1] + ws[2] + ws[3];
}

__global__ void scan_bsums(int* __restrict__ bsum, int nb, int* __restrict__ offsets, int n) {
    __shared__ int tmp[1024];
    int t = threadIdx.x;
    int v = (t < nb) ? bsum[t] : 0;
    tmp[t] = v;
    __syncthreads();
    for (int off = 1; off < 1024; off <<= 1) {
        int x = (t >= off) ? tmp[t - off] : 0;
        __syncthreads();
        tmp[t] += x;
        __syncthreads();
    }
    if (t < nb) bsum[t] = tmp[t] - v;
    if (t == 1023) offsets[n] = tmp[1023];
}

__global__ void scan_block(const int* __restrict__ counts, const int* __restrict__ bsum,
                           int* __restrict__ offsets, float* __restrict__ norm, int n) {
    __shared__ int tmp[1024];
    int base = blockIdx.x * 1024;
    int t = threadIdx.x;
    int i = base + t;
    int v = (i < n) ? counts[i] : 0;
    tmp[t] = v;
    __syncthreads();
    for (int off = 1; off < 1024; off <<= 1) {
        int x = (t >= off) ? tmp[t - off] : 0;
        __syncthreads();
        tmp[t] += x;
        __syncthreads();
    }
    if (i < n) {
        offsets[i] = bsum[blockIdx.x] + tmp[t] - v;
        norm[i] = rsqrtf((float)(v > 1 ? v : 1));
    }
}

__global__ void fill_csr(const int* __restrict__ src, const int* __restrict__ dst,
                         const int* __restrict__ offsets, int* __restrict__ cursor,
                         int* __restrict__ csr, int E) {
    int e = blockIdx.x * blockDim.x + threadIdx.x;
    if (e < E) {
        int v = dst[e];
        int pos = atomicAdd(&cursor[v], 1);
        csr[offsets[v] + pos] = src[e];
    }
}

// ---- hop 0: out = sigmoid(f.s)*f ; g0 = bf16(f*norm) --------------------
// 8 lanes per node, 8 dims (2 float4) per lane.

__global__ void hop0(const float4* __restrict__ feat, const float* __restrict__ s,
                     const float* __restrict__ norm, uint4* __restrict__ g,
                     float4* __restrict__ out, int n) {
    int t = blockIdx.x * blockDim.x + threadIdx.x;
    int node = t >> 3;
    int l = t & 7;
    if (node >= n) return;
    float4 f0 = feat[node * 16 + 2 * l];
    float4 f1 = feat[node * 16 + 2 * l + 1];
    const float4* s4 = (const float4*)s;
    float4 a = s4[2 * l], b = s4[2 * l + 1];
    float dot = f0.x * a.x + f0.y * a.y + f0.z * a.z + f0.w * a.w
              + f1.x * b.x + f1.y * b.y + f1.z * b.z + f1.w * b.w;
    #pragma unroll
    for (int m = 1; m <= 4; m <<= 1) dot += __shfl_xor(dot, m, 64);
    float sig = 1.0f / (1.0f + expf(-dot));
    out[node * 16 + 2 * l]     = f4scale(f0, sig);
    out[node * 16 + 2 * l + 1] = f4scale(f1, sig);
    float nv = norm[node];
    float v[8] = {f0.x * nv, f0.y * nv, f0.z * nv, f0.w * nv,
                  f1.x * nv, f1.y * nv, f1.z * nv, f1.w * nv};
    g[node * 8 + l] = pack_bf16x8(v);
}

// ---- hop t: gather-SpMM (bf16 rows) + fused attention-pool epilogue -----
// wave per node. lane = 8*g + l: 8 edge-subgroups g, 8 dim-lanes l.
// Edge indices preloaded (one per lane) and distributed by shuffle.
// IMPORTANT: the trip count is wave-uniform and every __shfl executes with
// ALL 64 lanes active and an in-range source lane (e = g+8j <= 63).
// Invalid (e >= dcap) lanes read row 0 (their source lane holds idx=0) and
// the accumulate is predicated off — no shfl under divergence.

__global__ void spmm_hop(const uint4* __restrict__ gin, const int* __restrict__ offsets,
                         const int* __restrict__ csr, const float* __restrict__ norm,
                         const float* __restrict__ s, uint4* __restrict__ gout,
                         float4* __restrict__ out, int n) {
    int lane = threadIdx.x & 63;
    int node = blockIdx.x * 4 + (threadIdx.x >> 6);
    if (node >= n) return;
    int g = lane >> 3;
    int l = lane & 7;
    int beg = offsets[node], end = offsets[node + 1];
    int deg = end - beg;
    int dcap = deg < 64 ? deg : 64;
    int idx = (lane < dcap) ? csr[beg + lane] : 0;

    float acc[8] = {0.f, 0.f, 0.f, 0.f, 0.f, 0.f, 0.f, 0.f};
    int trips = (dcap + 7) >> 3;     // wave-uniform (0..8)
    int j = 0;
    for (; j + 2 <= trips; j += 2) {
        int e0 = g + (j << 3);
        int e1 = e0 + 8;
        int u0 = __shfl(idx, e0, 64);     // all lanes active, e0<=63
        int u1 = __shfl(idx, e1, 64);     // e1 <= 63 since j+2<=trips<=8
        uint4 p0 = gin[(size_t)u0 * 8 + l];
        uint4 p1 = gin[(size_t)u1 * 8 + l];
        if (e0 < dcap) acc_bf16x8(p0, acc);
        if (e1 < dcap) acc_bf16x8(p1, acc);
    }
    if (j < trips) {
        int e0 = g + (j << 3);
        int u0 = __shfl(idx, e0, 64);
        uint4 p0 = gin[(size_t)u0 * 8 + l];
        if (e0 < dcap) acc_bf16x8(p0, acc);
    }
    for (int i = beg + 64 + g; i < end; i += 8) {   // deg>64: essentially never
        acc_bf16x8(gin[(size_t)csr[i] * 8 + l], acc);
    }

    // reduce across the 8 edge-subgroups (lane bits 3,4,5)
    #pragma unroll
    for (int m = 8; m <= 32; m <<= 1) {
        #pragma unroll
        for (int jj = 0; jj < 8; ++jj) acc[jj] += __shfl_xor(acc[jj], m, 64);
    }

    float nv = norm[node];
    float h[8];
    #pragma unroll
    for (int jj = 0; jj < 8; ++jj) h[jj] = acc[jj] * nv;

    const float4* s4 = (const float4*)s;
    float4 a = s4[2 * l], b = s4[2 * l + 1];
    float dot = h[0] * a.x + h[1] * a.y + h[2] * a.z + h[3] * a.w
              + h[4] * b.x + h[5] * b.y + h[6] * b.z + h[7] * b.w;
    #pragma unroll
    for (int m = 1; m <= 4; m <<= 1) dot += __shfl_xor(dot, m, 64);
    float sig = 1.0f / (1.0f + expf(-dot));

    if (g == 0) {
        float gv[8];
        #pragma unroll
        for (int jj = 0; jj < 8; ++jj) gv[jj] = h[jj] * nv;
        gout[node * 8 + l] = pack_bf16x8(gv);
        float4 o0 = out[node * 16 + 2 * l];
        float4 o1 = out[node * 16 + 2 * l + 1];
        o0.x += sig * h[0]; o0.y += sig * h[1]; o0.z += sig * h[2]; o0.w += sig * h[3];
        o1.x += sig * h[4]; o1.y += sig * h[5]; o1.z += sig * h[6]; o1.w += sig * h[7];
        out[node * 16 + 2 * l]     = o0;
        out[node * 16 + 2 * l + 1] = o1;
    }
}

// ---- launcher -----------------------------------------------------------

extern "C" void kernel_launch(void* const* d_in, const int* in_sizes, int n_in,
                              void* d_out, int out_size, void* d_ws, size_t ws_size,
                              hipStream_t stream) {
    const float* feat = (const float*)d_in[0];
    const float* s    = (const float*)d_in[1];
    const int*   src  = (const int*)d_in[2];
    const int*   dst  = (const int*)d_in[3];
    const int K = 10;

    int N = in_sizes[0] / D;
    int E = in_sizes[2];
    int nchunks = (N + 1023) / 1024;   // 98 for N=100000 (<= 1024 required)

    // workspace layout
    int*   counts  = (int*)d_ws;               // N
    int*   cursor  = counts + N;               // N
    int*   offsets = cursor + N;               // N+1
    int*   csr     = offsets + (N + 1);        // E
    float* norm    = (float*)(csr + E);        // N
    int*   bsum    = (int*)(norm + N);         // nchunks
    // align bf16 row buffers to 256B: each row = 8 uint4 = 128B = one cache line
    uintptr_t p = (uintptr_t)(bsum + nchunks);
    p = (p + 255) & ~(uintptr_t)255;
    uint4* g0 = (uint4*)p;                     // N*8 uint4 (bf16 rows)
    uint4* g1 = g0 + (size_t)N * 8;            // N*8 uint4

    hipMemsetAsync(counts, 0, sizeof(int) * 2 * (size_t)N, stream);  // counts + cursor

    count_edges<<<(E + 255) / 256, 256, 0, stream>>>(dst, counts, E);
    block_sums<<<nchunks, 256, 0, stream>>>(counts, bsum, N);
    scan_bsums<<<1, 1024, 0, stream>>>(bsum, nchunks, offsets, N);
    scan_block<<<nchunks, 1024, 0, stream>>>(counts, bsum, offsets, norm, N);
    fill_csr<<<(E + 255) / 256, 256, 0, stream>>>(src, dst, offsets, cursor, csr, E);

    hop0<<<(N * 8 + 255) / 256, 256, 0, stream>>>(
        (const float4*)feat, s, norm, g0, (float4*)d_out, N);

    uint4* gin = g0; uint4* gout = g1;
    for (int t = 0; t < K; ++t) {
        spmm_hop<<<(N + 3) / 4, 256, 0, stream>>>(
            gin, offsets, csr, norm, s, gout, (float4*)d_out, N);
        uint4* tmp = gin; gin = gout; gout = tmp;
    }
}